// Round 8
// baseline (15782.800 us; speedup 1.0000x reference)
//
#include <hip/hip_runtime.h>
#include <cstdint>
#include <cstddef>

// Problem constants (match reference)
#define B_    64
#define C_    128
#define T_    500
#define NRES  2048
#define NCLS  10

// Kernel org: 256 wgs (one per CU), 1024 threads = 16 waves (r6 skeleton —
// r7 proved 8 waves/2-per-SIMD starves latency hiding; keep >=4 waves/SIMD).
// wid = tid>>6 ; il = wid&7 (neuron) ; h = wid>>3 (batch half).
// G2 transposed: lane l of wave (il,h): blk = l&3, g = l>>2; owns block blk
// of batches bat0 = h*32+2g, bat1 = bat0+1.
// G1: each wave, lanes 0..31: ascending fmaf chain for bat = h*32+lane.
#define NWG   256
#define SL    8
#define NT    1024
#define WROW  520              // skewed words per 512-block row
#define WPIT  (4 * WROW)       // words per neuron row in LDS
#define XSP   132              // xs row pitch (words): 16-B aligned float4 rows

// BIT-EXACT MODEL (validated, absmax 0.0): G1: ascending fmaf chain (K=128).
// G2: KC=512 blocks [512,512,512,512], each an ascending masked rn-add chain
// starting at 0, folded left-to-right ((b0+b1)+b2)+b3.
// LIF: v = rn(rn(0.9f*v) + rn(g1+g2)). DO NOT CHANGE THE ARITHMETIC.
// G2 decode uses fmaf(w, bit?1.0f:0.0f, acc): fmaf(w,1,a)=rn(w+a),
// fmaf(w,0,a)=a — bit-exact vs masked rn-add (acc is never -0).

// r8 vs r6: (a) xs pitch 132 -> G1 = 32 aligned b128/wave (was 128 scalar
// b32), staging = 2 b128 writes/thread (was 8 b32); (b) G2 inner decode
// bfe+cvt+fma (6 VALU per element-pair, was 7-8). Sync/masks/transpose
// identical to r6 (14.03 ms).

// d_ws layout
#define WS_MASK0   0            // 16 KB: gm buf0 (4096 words: j*2+h)
#define WS_MASK1   16384        // 16 KB: gm buf1
#define WS_FLAG    32768        // 16 flags, 1024 B apart (16 KB)
#define WS_ARR     49152        // 256 arrival slots, 16 B apart (4 KB)
#define WS_WORDS   13312        // zero through 53248 B
#define NFLAG      16
#define CHKWG      (NWG - 1)

typedef float v2f __attribute__((ext_vector_type(2)));

struct SMem {
  float    WtT2[SL][WPIT];          // 66560 B : skewed W_res rows
  float    WinT2[SL][C_];           //  4096 B : W_in rows
  float    xs2[2][B_][XSP];         // 67584 B : x[:, :, t], double-buffered
  unsigned mask[B_][65];            // 16640 B : bat-major spike words s(t-1)
  double   clfred2[2][NCLS];        //   160 B : per-class partials, 2 bufs
};                                   // total 155040 B => 1 wg/CU (grid = 256)

__global__ void zero_ws_kernel(unsigned* __restrict__ p, int n) {
  int i = blockIdx.x * blockDim.x + threadIdx.x;
  if (i < n) p[i] = 0u;
}

// packed masked add via fma: bit -> 0.0/1.0 (bfe+cvt), chain-add folded
// into v_fmac. Bit-exact (see header note).
#define ACC2C(ACC, WF, M0, M1, JB) do {                                       \
  const float _b0 = (float)(((M0) >> (JB)) & 1u);                             \
  const float _b1 = (float)(((M1) >> (JB)) & 1u);                             \
  (ACC).x = fmaf((WF), _b0, (ACC).x);                                         \
  (ACC).y = fmaf((WF), _b1, (ACC).y);                                         \
} while (0)

// one step of the 32x32 bit-matrix transpose ladder (periodic masks)
#define BT_STEP(X, D, MLO) do {                                            \
  const unsigned _y = (unsigned)__shfl_xor((int)(X), (D), 64);             \
  (X) = (b & (D)) ? (((X) & ~(MLO)) | ((_y >> (D)) & (MLO)))               \
                  : (((X) & (MLO)) | ((_y << (D)) & ~(MLO)));              \
} while (0)

#define BT_ALL(X) do {                 \
  BT_STEP(X, 16, 0x0000FFFFu);         \
  BT_STEP(X,  8, 0x00FF00FFu);         \
  BT_STEP(X,  4, 0x0F0F0F0Fu);         \
  BT_STEP(X,  2, 0x33333333u);         \
  BT_STEP(X,  1, 0x55555555u);         \
} while (0)

__global__ void __launch_bounds__(NT, 4)
reservoir_kernel(const float* __restrict__ x, const float* __restrict__ Win,
                 const float* __restrict__ Wres, const float* __restrict__ Wclf,
                 float* __restrict__ out, unsigned char* __restrict__ ws) {
  __shared__ SMem sm;
  const int w   = blockIdx.x;
  const int tid = threadIdx.x;
  const int b   = tid & 63;          // lane index
  const int wid = tid >> 6;          // wave index 0..15
  const int il  = wid & 7;           // neuron within wg
  const int h   = wid >> 3;          // batch half
  const int blk = b & 3;             // G2: block owned by this lane
  const int g   = b >> 2;            // G2: batch pair group
  const int bat0 = h * 32 + g * 2;
  const int bat1 = bat0 + 1;
  const int iu  = __builtin_amdgcn_readfirstlane(w * SL + il);

  unsigned* gm0  = (unsigned*)(ws + WS_MASK0);
  unsigned* gm1  = (unsigned*)(ws + WS_MASK1);
  unsigned* flgb = (unsigned*)(ws + WS_FLAG);
  unsigned* arr  = (unsigned*)(ws + WS_ARR);
  unsigned* myflag = flgb + (w & (NFLAG - 1)) * 256;   // 1024-B spacing

  // ---- one-time: stage skewed W_res rows (16 float4 per thread) ----
  {
    const int j0 = tid * 16;
    #pragma unroll
    for (int r4 = 0; r4 < 4; ++r4) {
      const int j   = j0 + r4 * 4;
      const int il2 = j >> 11;
      const int pos = j & 2047;
      const int bk  = pos >> 9;
      const int s   = pos & 511;
      const float4 v4 = *(const float4*)(Wres + (size_t)(w * SL + il2) * NRES + pos);
      *(float4*)(&sm.WtT2[il2][bk * WROW + s]) = v4;
    }
  }
  {
    const int il2 = tid >> 7, c = tid & 127;
    sm.WinT2[il2][c] = Win[(size_t)(w * SL + il2) * C_ + c];
  }

  float v = 0.f;                   // reservoir membrane (lanes b<32)
  int   cntr = 0;
  double vc = 0.0;                 // classifier membrane
  int   cntc = 0;

  // prologue: stage xs(0) into buf0; prefetch x(:,:,1) into xv
  float xv[8];
  {
    const int p0 = tid * 8;
    float tmp[8];
    #pragma unroll
    for (int r = 0; r < 8; ++r) tmp[r] = x[(size_t)(p0 + r) * T_ + 0];
    float4 fa, fb;
    fa.x = tmp[0]; fa.y = tmp[1]; fa.z = tmp[2]; fa.w = tmp[3];
    fb.x = tmp[4]; fb.y = tmp[5]; fb.z = tmp[6]; fb.w = tmp[7];
    *(float4*)(&sm.xs2[0][p0 >> 7][p0 & 127]) = fa;
    *(float4*)(&sm.xs2[0][(p0 + 4) >> 7][(p0 + 4) & 127]) = fb;
    #pragma unroll
    for (int r = 0; r < 8; ++r) xv[r] = x[(size_t)(p0 + r) * T_ + 1];
  }

  for (int t = 0; t < T_; ++t) {
    unsigned* gprev = (t & 1) ? gm0 : gm1;   // s(t-1); t=0 reads zeroed gm1
    unsigned* gcur  = (t & 1) ? gm1 : gm0;

    // ---- load neuron-major ballots + 64x64 bit transpose -> sm.mask ----
    {
      const int i32 = b & 31, hh = b >> 5;
      #pragma unroll
      for (int kk = 0; kk < 4; ++kk) {
        const int k = (wid << 2) | kk;
        unsigned xw = __hip_atomic_load(gprev + (k * 32 + i32) * 2 + hh,
                                        __ATOMIC_RELAXED, __HIP_MEMORY_SCOPE_AGENT);
        BT_ALL(xw);
        sm.mask[b][k] = xw;
      }
    }
    __syncthreads();  // A: mask + xs(t) ready (also guards one-time stages)

    // ---- stage xs(t+1) into the other buffer (overlaps compute) ----
    if (t + 1 < T_) {
      const int p0 = tid * 8;
      float4 fa, fb;
      fa.x = xv[0]; fa.y = xv[1]; fa.z = xv[2]; fa.w = xv[3];
      fb.x = xv[4]; fb.y = xv[5]; fb.z = xv[6]; fb.w = xv[7];
      *(float4*)(&sm.xs2[(t + 1) & 1][p0 >> 7][p0 & 127]) = fa;
      *(float4*)(&sm.xs2[(t + 1) & 1][(p0 + 4) >> 7][(p0 + 4) & 127]) = fb;
      if (t + 2 < T_) {
        #pragma unroll
        for (int r = 0; r < 8; ++r) xv[r] = x[(size_t)(p0 + r) * T_ + (t + 2)];
      }
    }

    // ---- G1 (all waves, lanes 0..31): ascending fmaf chain, bat=h*32+b ----
    float g1 = 0.f;
    if (b < 32) {
      const int bat = h * 32 + b;
      const float4* __restrict__ winp = (const float4*)&sm.WinT2[il][0];
      const float4* __restrict__ xrp  = (const float4*)&sm.xs2[t & 1][bat][0];
      #pragma unroll 8
      for (int cq = 0; cq < 32; ++cq) {
        const float4 wv = winp[cq];
        const float4 xq = xrp[cq];
        g1 = fmaf(xq.x, wv.x, g1);
        g1 = fmaf(xq.y, wv.y, g1);
        g1 = fmaf(xq.z, wv.z, g1);
        g1 = fmaf(xq.w, wv.w, g1);
      }
    }

    // ---- G2 transposed: block blk of bat0 (lo) and bat1 (hi) ----
    v2f acc; acc.x = 0.f; acc.y = 0.f;
    {
      const float*    wbase = &sm.WtT2[il][blk * WROW];
      const unsigned* mr0   = &sm.mask[bat0][blk * 16];
      const unsigned* mr1   = &sm.mask[bat1][blk * 16];
      for (int wq = 0; wq < 16; ++wq) {
        const unsigned m0 = mr0[wq];
        const unsigned m1 = mr1[wq];
        const float4* q = (const float4*)(wbase + wq * 32);
        #pragma unroll
        for (int jq = 0; jq < 8; ++jq) {
          const float4 w4 = q[jq];
          const int jb = jq * 4;
          ACC2C(acc, w4.x, m0, m1, jb + 0);
          ACC2C(acc, w4.y, m0, m1, jb + 1);
          ACC2C(acc, w4.z, m0, m1, jb + 2);
          ACC2C(acc, w4.w, m0, m1, jb + 3);
        }
      }
    }
    const float aP = acc.x, aQ = acc.y;

    // ---- intra-wave fold to blk0 lanes: ((b0+b1)+b2)+b3 exact order ----
    const float p1 = __shfl_xor(aP, 1), q1 = __shfl_xor(aQ, 1);
    const float p2 = __shfl_xor(aP, 2), q2 = __shfl_xor(aQ, 2);
    const float p3 = __shfl_xor(aP, 3), q3 = __shfl_xor(aQ, 3);
    const float g2u0 = __fadd_rn(__fadd_rn(__fadd_rn(aP, p1), p2), p3);
    const float g2u1 = __fadd_rn(__fadd_rn(__fadd_rn(aQ, q1), q2), q3);

    // ---- redistribute to lane=bat (b<32), LIF, ballot, store gm word ----
    {
      const int src = (b >> 1) * 4;
      const float r0 = __shfl(g2u0, src, 64);
      const float r1 = __shfl(g2u1, src, 64);
      const float g2m = (b & 1) ? r1 : r0;
      const float I = __fadd_rn(g1, g2m);
      v = __fadd_rn(__fmul_rn(0.9f, v), I);
      bool s = (b < 32) && (v >= 1.0f);
      if (s) { v = 0.f; cntr++; }
      unsigned long long bal = __ballot(s);   // low 32 bits = bats h*32..+31
      if (b == 0)
        __hip_atomic_store(gcur + iu * 2 + h, (unsigned)bal,
                           __ATOMIC_RELAXED, __HIP_MEMORY_SCOPE_AGENT);
    }
    __syncthreads();  // B: all waves' gm stores drained (vmcnt 0 at barrier)

    // ---- FLAT ARRIVAL: own slot, release store (orders the gm stores) ----
    if (tid == 0)
      __hip_atomic_store(arr + w * 4, (unsigned)(t + 1),
                         __ATOMIC_RELEASE, __HIP_MEMORY_SCOPE_AGENT);

    // ---- CHECKER (wg 255, wave 0): poll all 256 slots, then release ----
    if (w == CHKWG && wid == 0) {
      const unsigned tgt = (unsigned)(t + 1);
      for (;;) {
        unsigned a0 = __hip_atomic_load(arr + (b +   0) * 4, __ATOMIC_RELAXED,
                                        __HIP_MEMORY_SCOPE_AGENT);
        unsigned a1 = __hip_atomic_load(arr + (b +  64) * 4, __ATOMIC_RELAXED,
                                        __HIP_MEMORY_SCOPE_AGENT);
        unsigned a2 = __hip_atomic_load(arr + (b + 128) * 4, __ATOMIC_RELAXED,
                                        __HIP_MEMORY_SCOPE_AGENT);
        unsigned a3 = __hip_atomic_load(arr + (b + 192) * 4, __ATOMIC_RELAXED,
                                        __HIP_MEMORY_SCOPE_AGENT);
        bool ok = (a0 >= tgt) & (a1 >= tgt) & (a2 >= tgt) & (a3 >= tgt);
        if (__all(ok)) break;
        __builtin_amdgcn_s_sleep(1);
      }
      if (b < NFLAG)
        __hip_atomic_store(flgb + b * 256, (unsigned)(t + 1),
                           __ATOMIC_RELEASE, __HIP_MEMORY_SCOPE_AGENT);
    }

    // ---- classifier partials for s(t-1): wave wid<10 = class wid (wg<64) ----
    if (w < B_ && wid < NCLS) {
      double pc = 0.0;
      if (t > 0) {
        const float* __restrict__ wc = Wclf + (size_t)wid * NRES + b;
        #pragma unroll 4
        for (int q = 0; q < 32; ++q) {
          const unsigned mw = sm.mask[w][(b >> 5) + 2 * q];
          const float wv = wc[q * 64];
          const unsigned keep =
              (unsigned)(((int)(mw << (31 - (b & 31)))) >> 31);
          pc += (double)__uint_as_float(keep & __float_as_uint(wv));
        }
      }
      #pragma unroll
      for (int off = 1; off < 64; off <<= 1)
        pc += __shfl_xor(pc, off, 64);
      if (b == 0) sm.clfred2[t & 1][wid] = pc;
    }

    // ---- classifier LIF: consume PREV step's partial (single value) ----
    if (w < B_ && tid < NCLS && t >= 2) {
      vc = 0.9 * vc + sm.clfred2[(t + 1) & 1][tid];
      if (vc >= 1.0) { vc = 0.0; cntc++; }
    }

    // ---- poll this wg's release flag ----
    if (tid == 0) {
      while (__hip_atomic_load(myflag, __ATOMIC_RELAXED,
                               __HIP_MEMORY_SCOPE_AGENT) < (unsigned)(t + 1))
        __builtin_amdgcn_s_sleep(1);
    }
    __syncthreads();  // D: whole wg proceeds past the grid barrier
  }

  // ======== epilogue ========
  // E1: deferred consume of partials written at t=499 (s(498), buf 1)
  if (w < B_ && tid < NCLS) {
    vc = 0.9 * vc + sm.clfred2[1][tid];
    if (vc >= 1.0) { vc = 0.0; cntc++; }
  }
  // E2: transpose s(499) (in gm1 since 499&1==1) -> sm.mask
  {
    const int i32 = b & 31, hh = b >> 5;
    #pragma unroll
    for (int kk = 0; kk < 4; ++kk) {
      const int k = (wid << 2) | kk;
      unsigned xw = __hip_atomic_load(gm1 + (k * 32 + i32) * 2 + hh,
                                      __ATOMIC_RELAXED, __HIP_MEMORY_SCOPE_AGENT);
      BT_ALL(xw);
      sm.mask[b][k] = xw;
    }
  }
  __syncthreads();
  // E3: classifier partials for s(499) -> clfred2[0]
  if (w < B_ && wid < NCLS) {
    double pc = 0.0;
    {
      const float* __restrict__ wc = Wclf + (size_t)wid * NRES + b;
      #pragma unroll 4
      for (int q = 0; q < 32; ++q) {
        const unsigned mw = sm.mask[w][(b >> 5) + 2 * q];
        const float wv = wc[q * 64];
        const unsigned keep =
            (unsigned)(((int)(mw << (31 - (b & 31)))) >> 31);
        pc += (double)__uint_as_float(keep & __float_as_uint(wv));
      }
    }
    #pragma unroll
    for (int off = 1; off < 64; off <<= 1)
      pc += __shfl_xor(pc, off, 64);
    if (b == 0) sm.clfred2[0][wid] = pc;
  }
  __syncthreads();
  // E4: final classifier LIF (s(499)) + output
  if (w < B_ && tid < NCLS) {
    vc = 0.9 * vc + sm.clfred2[0][tid];
    if (vc >= 1.0) cntc++;
    out[w * NCLS + tid] = (float)cntc;
  }
  // E5: reservoir spike counts: lane b<32 of wave (il,h) owns (h*32+b, iu)
  if (b < 32)
    out[B_ * NCLS + (size_t)(h * 32 + b) * NRES + w * SL + il] = (float)cntr;
}

extern "C" void kernel_launch(void* const* d_in, const int* in_sizes, int n_in,
                              void* d_out, int out_size, void* d_ws, size_t ws_size,
                              hipStream_t stream) {
  const float* x    = (const float*)d_in[0];   // (B, C, T)
  const float* Win  = (const float*)d_in[1];   // (NRES, C)
  const float* Wres = (const float*)d_in[2];   // (NRES, NRES)
  const float* Wclf = (const float*)d_in[3];   // (NCLS, NRES)
  float* out = (float*)d_out;
  unsigned char* ws = (unsigned char*)d_ws;

  hipLaunchKernelGGL(zero_ws_kernel, dim3((WS_WORDS + 255) / 256), dim3(256), 0, stream,
                     (unsigned*)ws, WS_WORDS);
  hipLaunchKernelGGL(reservoir_kernel, dim3(NWG), dim3(NT), 0, stream,
                     x, Win, Wres, Wclf, out, ws);
}

// Round 9
// 13844.740 us; speedup vs baseline: 1.1400x; 1.1400x over previous
//
#include <hip/hip_runtime.h>
#include <cstdint>
#include <cstddef>

// Problem constants (match reference)
#define B_    64
#define C_    128
#define T_    500
#define NRES  2048
#define NCLS  10

// Kernel org: 256 wgs (one per CU), 1024 threads = 16 waves (r6 skeleton:
// r7 proved 8 waves starves latency hiding; r8 proved the G2 decode is
// already optimal — shift/and matches v_bfe_i32, v2f add -> v_pk_add_f32).
// wid = tid>>6 ; il = wid&7 (neuron) ; h = wid>>3 (batch half).
// G2 transposed: lane l of wave (il,h): blk = l&3, g = l>>2; owns block blk
// of batches bat0 = h*32+2g, bat1 = bat0+1.
// G1: lanes 0..31 of each wave, one ascending fmaf chain for bat = h*32+lane.
#define NWG   256
#define SL    8
#define NT    1024
#define WROW  520              // skewed words per 512-block row
#define WPIT  (4 * WROW)       // words per neuron row in LDS

// BIT-EXACT MODEL (validated, absmax 0.0): G1: ascending fmaf chain (K=128).
// G2: KC=512 blocks [512,512,512,512], each an ascending masked rn-add chain
// starting at 0, folded left-to-right ((b0+b1)+b2)+b3.
// LIF: v = rn(rn(0.9f*v) + rn(g1+g2)). DO NOT CHANGE THE ARITHMETIC.

// r9 vs r6 (critical-path surgery, arithmetic untouched):
//  - G1(t+1) computed in the POLL WINDOW (after arrival, before flag check),
//    carried in a register; LIF uses g1 from the previous window / prologue.
//    Removes 512 b128 LDS reads + ~160 VALU per wave from the inter-barrier
//    critical path. Barrier B orders xs(t+1) staging vs the window reads.
//  - Barrier D + tid0-serial flag poll removed for w>=64 (192 wgs): every
//    wave polls the flag itself and proceeds into its private transpose
//    columns; barrier A re-syncs. w<64 keeps D (classifier waves read all
//    mask columns in the window; transpose must not overwrite early).
//  - #pragma unroll 4 on the G2 wq loop (loop/address overhead).

// d_ws layout
#define WS_MASK0   0            // 16 KB: gm buf0 (4096 words: j*2+h)
#define WS_MASK1   16384        // 16 KB: gm buf1
#define WS_FLAG    32768        // 16 flags, 1024 B apart (16 KB)
#define WS_ARR     49152        // 256 arrival slots, 16 B apart (4 KB)
#define WS_WORDS   13312        // zero through 53248 B
#define NFLAG      16
#define CHKWG      (NWG - 1)

typedef float v2f __attribute__((ext_vector_type(2)));

struct SMem {
  float    WtT2[SL][WPIT];          // 66560 B : skewed W_res rows
  float    WinT2[SL][C_];           //  4096 B : W_in rows
  float    xs2[2][B_][C_ + 1];      // 66048 B : x[:, :, t], double-buffered
  unsigned mask[B_][65];            // 16640 B : bat-major spike words s(t-1)
  double   clfred2[2][NCLS];        //   160 B : per-class partials, 2 bufs
};                                   // total 153504 B => 1 wg/CU (grid = 256)

__global__ void zero_ws_kernel(unsigned* __restrict__ p, int n) {
  int i = blockIdx.x * blockDim.x + threadIdx.x;
  if (i < n) p[i] = 0u;
}

// packed masked add: lanes' bat0/bat1 chains advance together.
// bfe(sign-extend bit)x2 + and x2 + <2 x float> fadd (RN per elem, bit-exact).
#define ACC2(ACC, WB, M0, M1, JB) do {                                        \
  const unsigned _lo = (unsigned)(((int)((M0) << (31 - (JB)))) >> 31) & (WB); \
  const unsigned _hi = (unsigned)(((int)((M1) << (31 - (JB)))) >> 31) & (WB); \
  v2f _m; _m.x = __uint_as_float(_lo); _m.y = __uint_as_float(_hi);           \
  (ACC) = (ACC) + _m;                                                         \
} while (0)

// one step of the 32x32 bit-matrix transpose ladder (periodic masks)
#define BT_STEP(X, D, MLO) do {                                            \
  const unsigned _y = (unsigned)__shfl_xor((int)(X), (D), 64);             \
  (X) = (b & (D)) ? (((X) & ~(MLO)) | ((_y >> (D)) & (MLO)))               \
                  : (((X) & (MLO)) | ((_y << (D)) & ~(MLO)));              \
} while (0)

#define BT_ALL(X) do {                 \
  BT_STEP(X, 16, 0x0000FFFFu);         \
  BT_STEP(X,  8, 0x00FF00FFu);         \
  BT_STEP(X,  4, 0x0F0F0F0Fu);         \
  BT_STEP(X,  2, 0x33333333u);         \
  BT_STEP(X,  1, 0x55555555u);         \
} while (0)

struct SMemRef;  // fwd not needed; use plain function

__device__ __forceinline__ float g1_compute(const float* __restrict__ winrow,
                                            const float* __restrict__ xrow) {
  float g1 = 0.f;
  const float4* __restrict__ winp = (const float4*)winrow;
  #pragma unroll 8
  for (int cq = 0; cq < 32; ++cq) {
    const float4 wv = winp[cq];
    const int c = cq * 4;
    g1 = fmaf(xrow[c + 0], wv.x, g1);
    g1 = fmaf(xrow[c + 1], wv.y, g1);
    g1 = fmaf(xrow[c + 2], wv.z, g1);
    g1 = fmaf(xrow[c + 3], wv.w, g1);
  }
  return g1;
}

__global__ void __launch_bounds__(NT, 4)
reservoir_kernel(const float* __restrict__ x, const float* __restrict__ Win,
                 const float* __restrict__ Wres, const float* __restrict__ Wclf,
                 float* __restrict__ out, unsigned char* __restrict__ ws) {
  __shared__ SMem sm;
  const int w   = blockIdx.x;
  const int tid = threadIdx.x;
  const int b   = tid & 63;          // lane index
  const int wid = tid >> 6;          // wave index 0..15
  const int il  = wid & 7;           // neuron within wg
  const int h   = wid >> 3;          // batch half
  const int blk = b & 3;             // G2: block owned by this lane
  const int g   = b >> 2;            // G2: batch pair group
  const int bat0 = h * 32 + g * 2;
  const int bat1 = bat0 + 1;
  const int iu  = __builtin_amdgcn_readfirstlane(w * SL + il);
  const int bat = h * 32 + (b & 31); // G1/LIF batch for lanes b<32

  unsigned* gm0  = (unsigned*)(ws + WS_MASK0);
  unsigned* gm1  = (unsigned*)(ws + WS_MASK1);
  unsigned* flgb = (unsigned*)(ws + WS_FLAG);
  unsigned* arr  = (unsigned*)(ws + WS_ARR);
  unsigned* myflag = flgb + (w & (NFLAG - 1)) * 256;   // 1024-B spacing

  // ---- one-time: stage skewed W_res rows (16 float4 per thread) ----
  {
    const int j0 = tid * 16;
    #pragma unroll
    for (int r4 = 0; r4 < 4; ++r4) {
      const int j   = j0 + r4 * 4;
      const int il2 = j >> 11;
      const int pos = j & 2047;
      const int bk  = pos >> 9;
      const int s   = pos & 511;
      const float4 v4 = *(const float4*)(Wres + (size_t)(w * SL + il2) * NRES + pos);
      *(float4*)(&sm.WtT2[il2][bk * WROW + s]) = v4;
    }
  }
  {
    const int il2 = tid >> 7, c = tid & 127;
    sm.WinT2[il2][c] = Win[(size_t)(w * SL + il2) * C_ + c];
  }

  float v = 0.f;                   // reservoir membrane (lanes b<32)
  int   cntr = 0;
  double vc = 0.0;                 // classifier membrane
  int   cntc = 0;

  // prologue: stage xs(0) into buf0; prefetch x(:,:,1) into xv
  float xv[8];
  {
    const int p0 = tid * 8;
    #pragma unroll
    for (int r = 0; r < 8; ++r) {
      float z = x[(size_t)(p0 + r) * T_ + 0];
      int p = p0 + r;
      sm.xs2[0][p >> 7][p & 127] = z;
    }
    #pragma unroll
    for (int r = 0; r < 8; ++r) xv[r] = x[(size_t)(p0 + r) * T_ + 1];
  }
  __syncthreads();  // prologue: one-time stages + xs(0) visible

  // g1 for t=0 (lanes b<32)
  float g1cur = 0.f;
  if (b < 32) g1cur = g1_compute(&sm.WinT2[il][0], &sm.xs2[0][bat][0]);

  for (int t = 0; t < T_; ++t) {
    unsigned* gprev = (t & 1) ? gm0 : gm1;   // s(t-1); t=0 reads zeroed gm1
    unsigned* gcur  = (t & 1) ? gm1 : gm0;

    // ---- load neuron-major ballots + 64x64 bit transpose -> sm.mask ----
    {
      const int i32 = b & 31, hh = b >> 5;
      #pragma unroll
      for (int kk = 0; kk < 4; ++kk) {
        const int k = (wid << 2) | kk;
        unsigned xw = __hip_atomic_load(gprev + (k * 32 + i32) * 2 + hh,
                                        __ATOMIC_RELAXED, __HIP_MEMORY_SCOPE_AGENT);
        BT_ALL(xw);
        sm.mask[b][k] = xw;
      }
    }
    __syncthreads();  // A: mask + xs(t) ready

    // ---- stage xs(t+1) into the other buffer; prefetch x(t+2) ----
    if (t + 1 < T_) {
      const int p0 = tid * 8;
      #pragma unroll
      for (int r = 0; r < 8; ++r) {
        int p = p0 + r;
        sm.xs2[(t + 1) & 1][p >> 7][p & 127] = xv[r];
      }
      if (t + 2 < T_) {
        #pragma unroll
        for (int r = 0; r < 8; ++r) xv[r] = x[(size_t)(p0 + r) * T_ + (t + 2)];
      }
    }

    // ---- G2 transposed: block blk of bat0 (lo) and bat1 (hi) ----
    v2f acc; acc.x = 0.f; acc.y = 0.f;
    {
      const float*    wbase = &sm.WtT2[il][blk * WROW];
      const unsigned* mr0   = &sm.mask[bat0][blk * 16];
      const unsigned* mr1   = &sm.mask[bat1][blk * 16];
      #pragma unroll 4
      for (int wq = 0; wq < 16; ++wq) {
        const unsigned m0 = mr0[wq];
        const unsigned m1 = mr1[wq];
        const float4* q = (const float4*)(wbase + wq * 32);
        #pragma unroll
        for (int jq = 0; jq < 8; ++jq) {
          const float4 w4 = q[jq];
          const int jb = jq * 4;
          ACC2(acc, __float_as_uint(w4.x), m0, m1, jb + 0);
          ACC2(acc, __float_as_uint(w4.y), m0, m1, jb + 1);
          ACC2(acc, __float_as_uint(w4.z), m0, m1, jb + 2);
          ACC2(acc, __float_as_uint(w4.w), m0, m1, jb + 3);
        }
      }
    }
    const float aP = acc.x, aQ = acc.y;

    // ---- intra-wave fold to blk0 lanes: ((b0+b1)+b2)+b3 exact order ----
    const float p1 = __shfl_xor(aP, 1), q1 = __shfl_xor(aQ, 1);
    const float p2 = __shfl_xor(aP, 2), q2 = __shfl_xor(aQ, 2);
    const float p3 = __shfl_xor(aP, 3), q3 = __shfl_xor(aQ, 3);
    const float g2u0 = __fadd_rn(__fadd_rn(__fadd_rn(aP, p1), p2), p3);
    const float g2u1 = __fadd_rn(__fadd_rn(__fadd_rn(aQ, q1), q2), q3);

    // ---- redistribute to lane=bat (b<32), LIF, ballot, store gm word ----
    {
      const int src = (b >> 1) * 4;
      const float r0 = __shfl(g2u0, src, 64);
      const float r1 = __shfl(g2u1, src, 64);
      const float g2m = (b & 1) ? r1 : r0;
      const float I = __fadd_rn(g1cur, g2m);
      v = __fadd_rn(__fmul_rn(0.9f, v), I);
      bool s = (b < 32) && (v >= 1.0f);
      if (s) { v = 0.f; cntr++; }
      unsigned long long bal = __ballot(s);   // low 32 bits = bats h*32..+31
      if (b == 0)
        __hip_atomic_store(gcur + iu * 2 + h, (unsigned)bal,
                           __ATOMIC_RELAXED, __HIP_MEMORY_SCOPE_AGENT);
    }
    __syncthreads();  // B: gm stores drained + xs(t+1) staging complete

    // ---- FLAT ARRIVAL: own slot, release store (orders the gm stores) ----
    if (tid == 0)
      __hip_atomic_store(arr + w * 4, (unsigned)(t + 1),
                         __ATOMIC_RELEASE, __HIP_MEMORY_SCOPE_AGENT);

    // ==== POLL WINDOW (off the inter-wg critical path) ====

    // ---- G1(t+1) for next step (lanes b<32); xs(t+1) ordered by B ----
    if (t + 1 < T_) {
      if (b < 32)
        g1cur = g1_compute(&sm.WinT2[il][0], &sm.xs2[(t + 1) & 1][bat][0]);
    }

    // ---- CHECKER (wg 255, wave 0): poll all 256 slots, then release ----
    if (w == CHKWG && wid == 0) {
      const unsigned tgt = (unsigned)(t + 1);
      for (;;) {
        unsigned a0 = __hip_atomic_load(arr + (b +   0) * 4, __ATOMIC_RELAXED,
                                        __HIP_MEMORY_SCOPE_AGENT);
        unsigned a1 = __hip_atomic_load(arr + (b +  64) * 4, __ATOMIC_RELAXED,
                                        __HIP_MEMORY_SCOPE_AGENT);
        unsigned a2 = __hip_atomic_load(arr + (b + 128) * 4, __ATOMIC_RELAXED,
                                        __HIP_MEMORY_SCOPE_AGENT);
        unsigned a3 = __hip_atomic_load(arr + (b + 192) * 4, __ATOMIC_RELAXED,
                                        __HIP_MEMORY_SCOPE_AGENT);
        bool ok = (a0 >= tgt) & (a1 >= tgt) & (a2 >= tgt) & (a3 >= tgt);
        if (__all(ok)) break;
        __builtin_amdgcn_s_sleep(1);
      }
      if (b < NFLAG)
        __hip_atomic_store(flgb + b * 256, (unsigned)(t + 1),
                           __ATOMIC_RELEASE, __HIP_MEMORY_SCOPE_AGENT);
    }

    if (w < B_) {
      // ---- classifier partials for s(t-1): wave wid<10 = class wid ----
      if (wid < NCLS) {
        double pc = 0.0;
        if (t > 0) {
          const float* __restrict__ wc = Wclf + (size_t)wid * NRES + b;
          #pragma unroll 4
          for (int q = 0; q < 32; ++q) {
            const unsigned mw = sm.mask[w][(b >> 5) + 2 * q];
            const float wv = wc[q * 64];
            const unsigned keep =
                (unsigned)(((int)(mw << (31 - (b & 31)))) >> 31);
            pc += (double)__uint_as_float(keep & __float_as_uint(wv));
          }
        }
        #pragma unroll
        for (int off = 1; off < 64; off <<= 1)
          pc += __shfl_xor(pc, off, 64);
        if (b == 0) sm.clfred2[t & 1][wid] = pc;
      }

      // ---- classifier LIF: consume PREV step's partial ----
      if (tid < NCLS && t >= 2) {
        vc = 0.9 * vc + sm.clfred2[(t + 1) & 1][tid];
        if (vc >= 1.0) { vc = 0.0; cntc++; }
      }

      // ---- classifier wgs: tid0 poll + barrier D (mask reads above must
      //      finish before next-step transpose overwrites sm.mask) ----
      if (tid == 0) {
        while (__hip_atomic_load(myflag, __ATOMIC_RELAXED,
                                 __HIP_MEMORY_SCOPE_AGENT) < (unsigned)(t + 1))
          __builtin_amdgcn_s_sleep(1);
      }
      __syncthreads();  // D
    } else {
      // ---- non-classifier wgs: PER-WAVE flag poll, no barrier D ----
      // (each wave proceeds into its private transpose columns; barrier A
      //  re-syncs before mask consumption; no wave reads sm.mask here)
      while (__hip_atomic_load(myflag, __ATOMIC_RELAXED,
                               __HIP_MEMORY_SCOPE_AGENT) < (unsigned)(t + 1))
        __builtin_amdgcn_s_sleep(1);
    }
  }

  // ======== epilogue ========
  // E1: deferred consume of partials written at t=499 (s(498), buf 1)
  if (w < B_ && tid < NCLS) {
    vc = 0.9 * vc + sm.clfred2[1][tid];
    if (vc >= 1.0) { vc = 0.0; cntc++; }
  }
  // E2: transpose s(499) (in gm1 since 499&1==1) -> sm.mask
  {
    const int i32 = b & 31, hh = b >> 5;
    #pragma unroll
    for (int kk = 0; kk < 4; ++kk) {
      const int k = (wid << 2) | kk;
      unsigned xw = __hip_atomic_load(gm1 + (k * 32 + i32) * 2 + hh,
                                      __ATOMIC_RELAXED, __HIP_MEMORY_SCOPE_AGENT);
      BT_ALL(xw);
      sm.mask[b][k] = xw;
    }
  }
  __syncthreads();
  // E3: classifier partials for s(499) -> clfred2[0]
  if (w < B_ && wid < NCLS) {
    double pc = 0.0;
    {
      const float* __restrict__ wc = Wclf + (size_t)wid * NRES + b;
      #pragma unroll 4
      for (int q = 0; q < 32; ++q) {
        const unsigned mw = sm.mask[w][(b >> 5) + 2 * q];
        const float wv = wc[q * 64];
        const unsigned keep =
            (unsigned)(((int)(mw << (31 - (b & 31)))) >> 31);
        pc += (double)__uint_as_float(keep & __float_as_uint(wv));
      }
    }
    #pragma unroll
    for (int off = 1; off < 64; off <<= 1)
      pc += __shfl_xor(pc, off, 64);
    if (b == 0) sm.clfred2[0][wid] = pc;
  }
  __syncthreads();
  // E4: final classifier LIF (s(499)) + output
  if (w < B_ && tid < NCLS) {
    vc = 0.9 * vc + sm.clfred2[0][tid];
    if (vc >= 1.0) cntc++;
    out[w * NCLS + tid] = (float)cntc;
  }
  // E5: reservoir spike counts: lane b<32 of wave (il,h) owns (h*32+b, iu)
  if (b < 32)
    out[B_ * NCLS + (size_t)bat * NRES + w * SL + il] = (float)cntr;
}

extern "C" void kernel_launch(void* const* d_in, const int* in_sizes, int n_in,
                              void* d_out, int out_size, void* d_ws, size_t ws_size,
                              hipStream_t stream) {
  const float* x    = (const float*)d_in[0];   // (B, C, T)
  const float* Win  = (const float*)d_in[1];   // (NRES, C)
  const float* Wres = (const float*)d_in[2];   // (NRES, NRES)
  const float* Wclf = (const float*)d_in[3];   // (NCLS, NRES)
  float* out = (float*)d_out;
  unsigned char* ws = (unsigned char*)d_ws;

  hipLaunchKernelGGL(zero_ws_kernel, dim3((WS_WORDS + 255) / 256), dim3(256), 0, stream,
                     (unsigned*)ws, WS_WORDS);
  hipLaunchKernelGGL(reservoir_kernel, dim3(NWG), dim3(NT), 0, stream,
                     x, Win, Wres, Wclf, out, ws);
}

// Round 10
// 13653.697 us; speedup vs baseline: 1.1559x; 1.0140x over previous
//
#include <hip/hip_runtime.h>
#include <cstdint>
#include <cstddef>

// Problem constants (match reference)
#define B_    64
#define C_    128
#define T_    500
#define NRES  2048
#define NCLS  10

// Kernel org: 256 wgs (one per CU), 1024 threads = 16 waves (r6 skeleton:
// r7 proved 8 waves starves latency hiding; r8 proved the G2 decode is
// already optimal — shift/and matches v_bfe_i32, v2f add -> v_pk_add_f32).
// wid = tid>>6 ; il = wid&7 (neuron) ; h = wid>>3 (batch half).
// G2 transposed: lane l of wave (il,h): blk = l&3, g = l>>2; owns block blk
// of batches bat0 = h*32+2g, bat1 = bat0+1.
// G1: lanes 0..31 of each wave, one ascending fmaf chain for bat = h*32+lane,
// computed in the POLL WINDOW for step t+1 (r9), carried in a register.
#define NWG   256
#define SL    8
#define NT    1024
#define WROW  520              // skewed words per 512-block row
#define WPIT  (4 * WROW)       // words per neuron row in LDS
#define XSP   132              // xs row pitch (words): 16-B aligned float4 rows

// BIT-EXACT MODEL (validated, absmax 0.0): G1: ascending fmaf chain (K=128).
// G2: KC=512 blocks [512,512,512,512], each an ascending masked rn-add chain
// starting at 0, folded left-to-right ((b0+b1)+b2)+b3.
// LIF: v = rn(rn(0.9f*v) + rn(g1+g2)). DO NOT CHANGE THE ARITHMETIC.

// r10 vs r9 (LDS-pipe relief + last barrier removed; arithmetic untouched):
//  - xs SINGLE-buffered, pitch 132 (16-B aligned): window-G1 = 32 aligned
//    b128/wave (was 128 scalar b32 at pitch 129); staging = 2 b128 stores.
//    Safe: G1(t) runs in window t-1; staging xs(t+1) after A(t) overwrites
//    nothing live (A orders prev-window reads; B orders staging vs G1next).
//  - mask DOUBLE-buffered in LDS: transpose(t)->maskb[t&1]; G2(t) + clf
//    window read it; earliest re-write is transpose(t+2), ordered by B(t+1).
//    => barrier D gone for ALL wgs; clf wgs per-wave poll; clfred2 ordering
//    via barrier A (write at window t, consume at window t+1).
//  - 2 barriers/step (A, B). LDS total ~138 KB.

// d_ws layout
#define WS_MASK0   0            // 16 KB: gm buf0 (4096 words: j*2+h)
#define WS_MASK1   16384        // 16 KB: gm buf1
#define WS_FLAG    32768        // 16 flags, 1024 B apart (16 KB)
#define WS_ARR     49152        // 256 arrival slots, 16 B apart (4 KB)
#define WS_WORDS   13312        // zero through 53248 B
#define NFLAG      16
#define CHKWG      (NWG - 1)

typedef float v2f __attribute__((ext_vector_type(2)));

struct SMem {
  float    WtT2[SL][WPIT];          // 66560 B : skewed W_res rows
  float    WinT2[SL][C_];           //  4096 B : W_in rows
  float    xs[B_][XSP];             // 33792 B : x[:, :, t], single buffer
  unsigned maskb[2][B_][65];        // 33280 B : bat-major spike words, 2 bufs
  double   clfred2[2][NCLS];        //   160 B : per-class partials, 2 bufs
};                                   // total 137888 B => 1 wg/CU (grid = 256)

__global__ void zero_ws_kernel(unsigned* __restrict__ p, int n) {
  int i = blockIdx.x * blockDim.x + threadIdx.x;
  if (i < n) p[i] = 0u;
}

// packed masked add: lanes' bat0/bat1 chains advance together.
// bfe(sign-extend bit)x2 + and x2 + <2 x float> fadd (RN per elem, bit-exact).
#define ACC2(ACC, WB, M0, M1, JB) do {                                        \
  const unsigned _lo = (unsigned)(((int)((M0) << (31 - (JB)))) >> 31) & (WB); \
  const unsigned _hi = (unsigned)(((int)((M1) << (31 - (JB)))) >> 31) & (WB); \
  v2f _m; _m.x = __uint_as_float(_lo); _m.y = __uint_as_float(_hi);           \
  (ACC) = (ACC) + _m;                                                         \
} while (0)

// one step of the 32x32 bit-matrix transpose ladder (periodic masks)
#define BT_STEP(X, D, MLO) do {                                            \
  const unsigned _y = (unsigned)__shfl_xor((int)(X), (D), 64);             \
  (X) = (b & (D)) ? (((X) & ~(MLO)) | ((_y >> (D)) & (MLO)))               \
                  : (((X) & (MLO)) | ((_y << (D)) & ~(MLO)));              \
} while (0)

#define BT_ALL(X) do {                 \
  BT_STEP(X, 16, 0x0000FFFFu);         \
  BT_STEP(X,  8, 0x00FF00FFu);         \
  BT_STEP(X,  4, 0x0F0F0F0Fu);         \
  BT_STEP(X,  2, 0x33333333u);         \
  BT_STEP(X,  1, 0x55555555u);         \
} while (0)

__device__ __forceinline__ float g1_compute(const float* __restrict__ winrow,
                                            const float* __restrict__ xrow) {
  float g1 = 0.f;
  const float4* __restrict__ winp = (const float4*)winrow;
  const float4* __restrict__ xrp  = (const float4*)xrow;
  #pragma unroll 8
  for (int cq = 0; cq < 32; ++cq) {
    const float4 wv = winp[cq];
    const float4 xq = xrp[cq];
    g1 = fmaf(xq.x, wv.x, g1);
    g1 = fmaf(xq.y, wv.y, g1);
    g1 = fmaf(xq.z, wv.z, g1);
    g1 = fmaf(xq.w, wv.w, g1);
  }
  return g1;
}

__global__ void __launch_bounds__(NT, 4)
reservoir_kernel(const float* __restrict__ x, const float* __restrict__ Win,
                 const float* __restrict__ Wres, const float* __restrict__ Wclf,
                 float* __restrict__ out, unsigned char* __restrict__ ws) {
  __shared__ SMem sm;
  const int w   = blockIdx.x;
  const int tid = threadIdx.x;
  const int b   = tid & 63;          // lane index
  const int wid = tid >> 6;          // wave index 0..15
  const int il  = wid & 7;           // neuron within wg
  const int h   = wid >> 3;          // batch half
  const int blk = b & 3;             // G2: block owned by this lane
  const int g   = b >> 2;            // G2: batch pair group
  const int bat0 = h * 32 + g * 2;
  const int bat1 = bat0 + 1;
  const int iu  = __builtin_amdgcn_readfirstlane(w * SL + il);
  const int bat = h * 32 + (b & 31); // G1/LIF batch for lanes b<32

  unsigned* gm0  = (unsigned*)(ws + WS_MASK0);
  unsigned* gm1  = (unsigned*)(ws + WS_MASK1);
  unsigned* flgb = (unsigned*)(ws + WS_FLAG);
  unsigned* arr  = (unsigned*)(ws + WS_ARR);
  unsigned* myflag = flgb + (w & (NFLAG - 1)) * 256;   // 1024-B spacing

  // ---- one-time: stage skewed W_res rows (16 float4 per thread) ----
  {
    const int j0 = tid * 16;
    #pragma unroll
    for (int r4 = 0; r4 < 4; ++r4) {
      const int j   = j0 + r4 * 4;
      const int il2 = j >> 11;
      const int pos = j & 2047;
      const int bk  = pos >> 9;
      const int s   = pos & 511;
      const float4 v4 = *(const float4*)(Wres + (size_t)(w * SL + il2) * NRES + pos);
      *(float4*)(&sm.WtT2[il2][bk * WROW + s]) = v4;
    }
  }
  {
    const int il2 = tid >> 7, c = tid & 127;
    sm.WinT2[il2][c] = Win[(size_t)(w * SL + il2) * C_ + c];
  }

  float v = 0.f;                   // reservoir membrane (lanes b<32)
  int   cntr = 0;
  double vc = 0.0;                 // classifier membrane
  int   cntc = 0;

  // prologue: stage xs(0); prefetch x(:,:,1) into xv
  float xv[8];
  {
    const int p0 = tid * 8;
    float tmp[8];
    #pragma unroll
    for (int r = 0; r < 8; ++r) tmp[r] = x[(size_t)(p0 + r) * T_ + 0];
    float4 fa, fb;
    fa.x = tmp[0]; fa.y = tmp[1]; fa.z = tmp[2]; fa.w = tmp[3];
    fb.x = tmp[4]; fb.y = tmp[5]; fb.z = tmp[6]; fb.w = tmp[7];
    const int row = p0 >> 7, col = p0 & 127;
    *(float4*)(&sm.xs[row][col])     = fa;
    *(float4*)(&sm.xs[row][col + 4]) = fb;
    #pragma unroll
    for (int r = 0; r < 8; ++r) xv[r] = x[(size_t)(p0 + r) * T_ + 1];
  }
  __syncthreads();  // prologue: one-time stages + xs(0) visible

  // g1 for t=0 (lanes b<32)
  float g1cur = 0.f;
  if (b < 32) g1cur = g1_compute(&sm.WinT2[il][0], &sm.xs[bat][0]);

  for (int t = 0; t < T_; ++t) {
    unsigned* gprev = (t & 1) ? gm0 : gm1;   // s(t-1); t=0 reads zeroed gm1
    unsigned* gcur  = (t & 1) ? gm1 : gm0;
    unsigned (* __restrict__ mk)[65] = sm.maskb[t & 1];

    // ---- load neuron-major ballots + 64x64 bit transpose -> maskb[t&1] ----
    {
      const int i32 = b & 31, hh = b >> 5;
      #pragma unroll
      for (int kk = 0; kk < 4; ++kk) {
        const int k = (wid << 2) | kk;
        unsigned xw = __hip_atomic_load(gprev + (k * 32 + i32) * 2 + hh,
                                        __ATOMIC_RELAXED, __HIP_MEMORY_SCOPE_AGENT);
        BT_ALL(xw);
        mk[b][k] = xw;
      }
    }
    __syncthreads();  // A: mask ready; prev-window G1 reads done (xs reusable)

    // ---- stage xs(t+1) (overwrites xs(t) — no longer live); prefetch ----
    if (t + 1 < T_) {
      const int p0 = tid * 8;
      float4 fa, fb;
      fa.x = xv[0]; fa.y = xv[1]; fa.z = xv[2]; fa.w = xv[3];
      fb.x = xv[4]; fb.y = xv[5]; fb.z = xv[6]; fb.w = xv[7];
      const int row = p0 >> 7, col = p0 & 127;
      *(float4*)(&sm.xs[row][col])     = fa;
      *(float4*)(&sm.xs[row][col + 4]) = fb;
      if (t + 2 < T_) {
        #pragma unroll
        for (int r = 0; r < 8; ++r) xv[r] = x[(size_t)(p0 + r) * T_ + (t + 2)];
      }
    }

    // ---- G2 transposed: block blk of bat0 (lo) and bat1 (hi) ----
    v2f acc; acc.x = 0.f; acc.y = 0.f;
    {
      const float*    wbase = &sm.WtT2[il][blk * WROW];
      const unsigned* mr0   = &mk[bat0][blk * 16];
      const unsigned* mr1   = &mk[bat1][blk * 16];
      #pragma unroll 4
      for (int wq = 0; wq < 16; ++wq) {
        const unsigned m0 = mr0[wq];
        const unsigned m1 = mr1[wq];
        const float4* q = (const float4*)(wbase + wq * 32);
        #pragma unroll
        for (int jq = 0; jq < 8; ++jq) {
          const float4 w4 = q[jq];
          const int jb = jq * 4;
          ACC2(acc, __float_as_uint(w4.x), m0, m1, jb + 0);
          ACC2(acc, __float_as_uint(w4.y), m0, m1, jb + 1);
          ACC2(acc, __float_as_uint(w4.z), m0, m1, jb + 2);
          ACC2(acc, __float_as_uint(w4.w), m0, m1, jb + 3);
        }
      }
    }
    const float aP = acc.x, aQ = acc.y;

    // ---- intra-wave fold to blk0 lanes: ((b0+b1)+b2)+b3 exact order ----
    const float p1 = __shfl_xor(aP, 1), q1 = __shfl_xor(aQ, 1);
    const float p2 = __shfl_xor(aP, 2), q2 = __shfl_xor(aQ, 2);
    const float p3 = __shfl_xor(aP, 3), q3 = __shfl_xor(aQ, 3);
    const float g2u0 = __fadd_rn(__fadd_rn(__fadd_rn(aP, p1), p2), p3);
    const float g2u1 = __fadd_rn(__fadd_rn(__fadd_rn(aQ, q1), q2), q3);

    // ---- redistribute to lane=bat (b<32), LIF, ballot, store gm word ----
    {
      const int src = (b >> 1) * 4;
      const float r0 = __shfl(g2u0, src, 64);
      const float r1 = __shfl(g2u1, src, 64);
      const float g2m = (b & 1) ? r1 : r0;
      const float I = __fadd_rn(g1cur, g2m);
      v = __fadd_rn(__fmul_rn(0.9f, v), I);
      bool s = (b < 32) && (v >= 1.0f);
      if (s) { v = 0.f; cntr++; }
      unsigned long long bal = __ballot(s);   // low 32 bits = bats h*32..+31
      if (b == 0)
        __hip_atomic_store(gcur + iu * 2 + h, (unsigned)bal,
                           __ATOMIC_RELAXED, __HIP_MEMORY_SCOPE_AGENT);
    }
    __syncthreads();  // B: gm stores drained + xs(t+1) staging complete

    // ---- FLAT ARRIVAL: own slot, release store (orders the gm stores) ----
    if (tid == 0)
      __hip_atomic_store(arr + w * 4, (unsigned)(t + 1),
                         __ATOMIC_RELEASE, __HIP_MEMORY_SCOPE_AGENT);

    // ==== POLL WINDOW (off the inter-wg critical path) ====

    // ---- G1(t+1) for next step (lanes b<32); xs(t+1) ordered by B ----
    if (t + 1 < T_ && b < 32)
      g1cur = g1_compute(&sm.WinT2[il][0], &sm.xs[bat][0]);

    // ---- CHECKER (wg 255, wave 0): poll all 256 slots, then release ----
    if (w == CHKWG && wid == 0) {
      const unsigned tgt = (unsigned)(t + 1);
      for (;;) {
        unsigned a0 = __hip_atomic_load(arr + (b +   0) * 4, __ATOMIC_RELAXED,
                                        __HIP_MEMORY_SCOPE_AGENT);
        unsigned a1 = __hip_atomic_load(arr + (b +  64) * 4, __ATOMIC_RELAXED,
                                        __HIP_MEMORY_SCOPE_AGENT);
        unsigned a2 = __hip_atomic_load(arr + (b + 128) * 4, __ATOMIC_RELAXED,
                                        __HIP_MEMORY_SCOPE_AGENT);
        unsigned a3 = __hip_atomic_load(arr + (b + 192) * 4, __ATOMIC_RELAXED,
                                        __HIP_MEMORY_SCOPE_AGENT);
        bool ok = (a0 >= tgt) & (a1 >= tgt) & (a2 >= tgt) & (a3 >= tgt);
        if (__all(ok)) break;
        __builtin_amdgcn_s_sleep(1);
      }
      if (b < NFLAG)
        __hip_atomic_store(flgb + b * 256, (unsigned)(t + 1),
                           __ATOMIC_RELEASE, __HIP_MEMORY_SCOPE_AGENT);
    }

    // ---- classifier (wg w<64): partial for s(t-1) from maskb[t&1];
    //      safe: earliest re-write of this buffer is transpose(t+2),
    //      ordered after these reads by barrier B(t+1). ----
    if (w < B_) {
      if (wid < NCLS) {
        double pc = 0.0;
        if (t > 0) {
          const float* __restrict__ wc = Wclf + (size_t)wid * NRES + b;
          #pragma unroll 4
          for (int q = 0; q < 32; ++q) {
            const unsigned mw = mk[w][(b >> 5) + 2 * q];
            const float wv = wc[q * 64];
            const unsigned keep =
                (unsigned)(((int)(mw << (31 - (b & 31)))) >> 31);
            pc += (double)__uint_as_float(keep & __float_as_uint(wv));
          }
        }
        #pragma unroll
        for (int off = 1; off < 64; off <<= 1)
          pc += __shfl_xor(pc, off, 64);
        if (b == 0) sm.clfred2[t & 1][wid] = pc;
      }
      // consume PREV step's partial (written window t-1; ordered by A(t))
      if (tid < NCLS && t >= 2) {
        vc = 0.9 * vc + sm.clfred2[(t + 1) & 1][tid];
        if (vc >= 1.0) { vc = 0.0; cntc++; }
      }
    }

    // ---- PER-WAVE flag poll (all wgs; no barrier D) ----
    while (__hip_atomic_load(myflag, __ATOMIC_RELAXED,
                             __HIP_MEMORY_SCOPE_AGENT) < (unsigned)(t + 1))
      __builtin_amdgcn_s_sleep(1);
  }

  // ======== epilogue ========
  __syncthreads();  // order window-499 clfred2 writes before E1 reads
  // E1: deferred consume of partials written at t=499 (s(498), buf 1)
  if (w < B_ && tid < NCLS) {
    vc = 0.9 * vc + sm.clfred2[1][tid];
    if (vc >= 1.0) { vc = 0.0; cntc++; }
  }
  // E2: transpose s(499) (in gm1 since 499&1==1) -> maskb[0]
  {
    const int i32 = b & 31, hh = b >> 5;
    #pragma unroll
    for (int kk = 0; kk < 4; ++kk) {
      const int k = (wid << 2) | kk;
      unsigned xw = __hip_atomic_load(gm1 + (k * 32 + i32) * 2 + hh,
                                      __ATOMIC_RELAXED, __HIP_MEMORY_SCOPE_AGENT);
      BT_ALL(xw);
      sm.maskb[0][b][k] = xw;
    }
  }
  __syncthreads();
  // E3: classifier partials for s(499) -> clfred2[0]
  if (w < B_ && wid < NCLS) {
    double pc = 0.0;
    {
      const float* __restrict__ wc = Wclf + (size_t)wid * NRES + b;
      #pragma unroll 4
      for (int q = 0; q < 32; ++q) {
        const unsigned mw = sm.maskb[0][w][(b >> 5) + 2 * q];
        const float wv = wc[q * 64];
        const unsigned keep =
            (unsigned)(((int)(mw << (31 - (b & 31)))) >> 31);
        pc += (double)__uint_as_float(keep & __float_as_uint(wv));
      }
    }
    #pragma unroll
    for (int off = 1; off < 64; off <<= 1)
      pc += __shfl_xor(pc, off, 64);
    if (b == 0) sm.clfred2[0][wid] = pc;
  }
  __syncthreads();
  // E4: final classifier LIF (s(499)) + output
  if (w < B_ && tid < NCLS) {
    vc = 0.9 * vc + sm.clfred2[0][tid];
    if (vc >= 1.0) cntc++;
    out[w * NCLS + tid] = (float)cntc;
  }
  // E5: reservoir spike counts: lane b<32 of wave (il,h) owns (h*32+b, iu)
  if (b < 32)
    out[B_ * NCLS + (size_t)bat * NRES + w * SL + il] = (float)cntr;
}

extern "C" void kernel_launch(void* const* d_in, const int* in_sizes, int n_in,
                              void* d_out, int out_size, void* d_ws, size_t ws_size,
                              hipStream_t stream) {
  const float* x    = (const float*)d_in[0];   // (B, C, T)
  const float* Win  = (const float*)d_in[1];   // (NRES, C)
  const float* Wres = (const float*)d_in[2];   // (NRES, NRES)
  const float* Wclf = (const float*)d_in[3];   // (NCLS, NRES)
  float* out = (float*)d_out;
  unsigned char* ws = (unsigned char*)d_ws;

  hipLaunchKernelGGL(zero_ws_kernel, dim3((WS_WORDS + 255) / 256), dim3(256), 0, stream,
                     (unsigned*)ws, WS_WORDS);
  hipLaunchKernelGGL(reservoir_kernel, dim3(NWG), dim3(NT), 0, stream,
                     x, Win, Wres, Wclf, out, ws);
}